// Round 1
// baseline (1857.892 us; speedup 1.0000x reference)
//
#include <hip/hip_runtime.h>
#include <math.h>

#define NB 32
#define NG 512
#define NC 384
#define NH 768

// ---------------- GEMM: C = op(A @ Bw + bias), A: MxK row-major, Bw: KxN row-major
// mode 0: relu      mode 1: divide by 0.1 (scores / TAU)
__global__ __launch_bounds__(256) void gemm_bias(
    const float* __restrict__ A, const float* __restrict__ Bw,
    const float* __restrict__ bias, float* __restrict__ Co,
    int M, int N, int K, int mode)
{
    __shared__ float sA[16][64];
    __shared__ float sB[16][64];
    int mtiles = M >> 6;
    int bm = (blockIdx.x % mtiles) << 6;
    int bn = (blockIdx.x / mtiles) << 6;
    int t = threadIdx.x;
    int tx = t & 15, ty = t >> 4;
    int la_m = t >> 2;          // 0..63
    int la_q = (t & 3) << 2;    // k offset 0,4,8,12
    int lb_k = t >> 4;          // 0..15
    int lb_n = (t & 15) << 2;   // 0..60
    const float* Aptr = A + (size_t)(bm + la_m) * K + la_q;
    const float* Bptr = Bw + (size_t)lb_k * N + bn + lb_n;
    float acc[4][4];
#pragma unroll
    for (int i = 0; i < 4; i++)
#pragma unroll
        for (int j = 0; j < 4; j++) acc[i][j] = 0.f;

    for (int k0 = 0; k0 < K; k0 += 16) {
        float4 av = *(const float4*)(Aptr + k0);
        float4 bv = *(const float4*)(Bptr + (size_t)k0 * N);
        __syncthreads();
        sA[la_q + 0][la_m] = av.x;
        sA[la_q + 1][la_m] = av.y;
        sA[la_q + 2][la_m] = av.z;
        sA[la_q + 3][la_m] = av.w;
        *(float4*)&sB[lb_k][lb_n] = bv;
        __syncthreads();
#pragma unroll
        for (int kk = 0; kk < 16; kk++) {
            float a0 = sA[kk][(ty << 2) + 0], a1 = sA[kk][(ty << 2) + 1];
            float a2 = sA[kk][(ty << 2) + 2], a3 = sA[kk][(ty << 2) + 3];
            float b0 = sB[kk][(tx << 2) + 0], b1 = sB[kk][(tx << 2) + 1];
            float b2 = sB[kk][(tx << 2) + 2], b3 = sB[kk][(tx << 2) + 3];
            acc[0][0] += a0 * b0; acc[0][1] += a0 * b1; acc[0][2] += a0 * b2; acc[0][3] += a0 * b3;
            acc[1][0] += a1 * b0; acc[1][1] += a1 * b1; acc[1][2] += a1 * b2; acc[1][3] += a1 * b3;
            acc[2][0] += a2 * b0; acc[2][1] += a2 * b1; acc[2][2] += a2 * b2; acc[2][3] += a2 * b3;
            acc[3][0] += a3 * b0; acc[3][1] += a3 * b1; acc[3][2] += a3 * b2; acc[3][3] += a3 * b3;
        }
    }
#pragma unroll
    for (int i = 0; i < 4; i++) {
        int row = bm + (ty << 2) + i;
        float vals[4];
#pragma unroll
        for (int j = 0; j < 4; j++) {
            float val = acc[i][j] + bias[bn + (tx << 2) + j];
            vals[j] = (mode == 0) ? fmaxf(val, 0.f) : val / 0.1f;
        }
        float4 o; o.x = vals[0]; o.y = vals[1]; o.z = vals[2]; o.w = vals[3];
        *(float4*)(Co + (size_t)row * N + bn + (tx << 2)) = o;
    }
}

// ---------------- Sinkhorn: u_i = -LSE_j(A0_ij + v_j)   (one wave per row)
__global__ __launch_bounds__(256) void row_lse(
    const float* __restrict__ A0, const float* __restrict__ vv,
    float* __restrict__ uu)
{
    int wid = blockIdx.x * 4 + (threadIdx.x >> 6);   // global row over NB*NG
    int lane = threadIdx.x & 63;
    int b = wid >> 9;
    const float* row = A0 + (size_t)wid * NG;
    const float* vb = vv + (b << 9);
    float x[8];
    float m = -INFINITY;
#pragma unroll
    for (int e = 0; e < 8; e++) {
        int j = (e << 6) + lane;
        x[e] = row[j] + vb[j];
        m = fmaxf(m, x[e]);
    }
#pragma unroll
    for (int off = 1; off < 64; off <<= 1) m = fmaxf(m, __shfl_xor(m, off));
    float s = 0.f;
#pragma unroll
    for (int e = 0; e < 8; e++) s += expf(x[e] - m);
#pragma unroll
    for (int off = 1; off < 64; off <<= 1) s += __shfl_xor(s, off);
    if (lane == 0) uu[wid] = -(m + logf(s));
}

// ---------------- Sinkhorn col step stage A: partial online LSE over 64-row chunks
__global__ __launch_bounds__(256) void col_partial(
    const float* __restrict__ A0, const float* __restrict__ uu,
    float* __restrict__ pm, float* __restrict__ ps)
{
    int blk = blockIdx.x;          // NB * 2 * 8 = 512 blocks
    int b = blk >> 4;
    int cc = blk & 1;
    int rc = (blk >> 1) & 7;
    int j = (cc << 8) + threadIdx.x;
    const float* base = A0 + ((size_t)(b << 9) + (rc << 6)) * NG + j;
    const float* ub = uu + (b << 9) + (rc << 6);
    float m = -INFINITY, s = 0.f;
    for (int i = 0; i < 64; i++) {
        float x = base[(size_t)i * NG] + ub[i];
        if (x > m) { s = s * expf(m - x) + 1.f; m = x; }
        else s += expf(x - m);
    }
    int o = ((b << 3) + rc) * NG + j;
    pm[o] = m; ps[o] = s;
}

// ---------------- Sinkhorn col step stage B: combine 8 partials -> v_j
__global__ __launch_bounds__(256) void col_combine(
    const float* __restrict__ pm, const float* __restrict__ ps,
    float* __restrict__ vv)
{
    int tid = blockIdx.x * 256 + threadIdx.x;  // NB*NG
    int b = tid >> 9, j = tid & 511;
    float M = -INFINITY;
#pragma unroll
    for (int rc = 0; rc < 8; rc++) M = fmaxf(M, pm[((b << 3) + rc) * NG + j]);
    float S = 0.f;
#pragma unroll
    for (int rc = 0; rc < 8; rc++) {
        int o = ((b << 3) + rc) * NG + j;
        S += ps[o] * expf(pm[o] - M);
    }
    vv[tid] = -(M + logf(S));
}

// ---------------- Greedy assignment, one block per batch, 512 threads.
// P_ij = exp(A0_ij + u_i + v_j). Exactly replicates: repeatedly take the global
// argmax (ties: lowest flat index r*G+c) over entries with free row & free col.
__global__ __launch_bounds__(512) void greedy(
    const float* __restrict__ A0, const float* __restrict__ uu,
    const float* __restrict__ vv, int* __restrict__ permInt,
    float* __restrict__ permOutF)
{
    int b = blockIdx.x;
    __shared__ float su[NG], sv[NG];
    __shared__ float rbVal[NG];
    __shared__ int rbCol[NG];
    __shared__ unsigned long long colFree[8];
    __shared__ int sperm[NG];
    __shared__ int dirty[NG];
    __shared__ int dirtyCount;
    __shared__ float wVal[8];
    __shared__ int wIdx[8];
    __shared__ int bestC;

    int t = threadIdx.x;
    int lane = t & 63;
    int w = t >> 6;

    su[t] = uu[b * NG + t];
    sv[t] = vv[b * NG + t];
    if (t < 8) colFree[t] = ~0ULL;
    if (t == 0) dirtyCount = 0;
    __syncthreads();

    const float* Ab = A0 + (size_t)b * NG * NG;

    // init per-row best over all columns (val desc, col asc)
    for (int r = w; r < NG; r += 8) {
        const float* rowp = Ab + (size_t)r * NG;
        float uu_r = su[r];
        float bv = -1.0f; int bj = 0;
#pragma unroll
        for (int e = 0; e < 8; e++) {
            int j = (e << 6) + lane;
            float p = expf(rowp[j] + uu_r + sv[j]);
            if (p > bv) { bv = p; bj = j; }   // ascending j keeps lowest col on tie
        }
#pragma unroll
        for (int off = 1; off < 64; off <<= 1) {
            float ov = __shfl_xor(bv, off); int oj = __shfl_xor(bj, off);
            if (ov > bv || (ov == bv && oj < bj)) { bv = ov; bj = oj; }
        }
        if (lane == 0) { rbVal[r] = bv; rbCol[r] = bj; }
    }
    __syncthreads();

    for (int step = 0; step < NG; step++) {
        // block argmax over rows: key = (val desc, flat index asc)
        float v0 = rbVal[t];
        int f0 = t * NG + rbCol[t];
#pragma unroll
        for (int off = 1; off < 64; off <<= 1) {
            float ov = __shfl_xor(v0, off); int of = __shfl_xor(f0, off);
            if (ov > v0 || (ov == v0 && of < f0)) { v0 = ov; f0 = of; }
        }
        if (lane == 0) { wVal[w] = v0; wIdx[w] = f0; }
        __syncthreads();
        if (t == 0) {
            float bv = wVal[0]; int bf = wIdx[0];
#pragma unroll
            for (int k = 1; k < 8; k++) {
                if (wVal[k] > bv || (wVal[k] == bv && wIdx[k] < bf)) { bv = wVal[k]; bf = wIdx[k]; }
            }
            int r = bf >> 9, c = bf & 511;
            bestC = c;
            sperm[r] = c;
            rbVal[r] = -1.0f;                    // row no longer free
            colFree[c >> 6] &= ~(1ULL << (c & 63));
            dirtyCount = 0;
        }
        __syncthreads();
        int c = bestC;
        // rows whose cached argmax column just got taken need a rescan
        if (rbVal[t] >= 0.0f && rbCol[t] == c) {
            int d = atomicAdd(&dirtyCount, 1);
            dirty[d] = t;
        }
        __syncthreads();
        int nd = dirtyCount;
        for (int d = w; d < nd; d += 8) {
            int r = dirty[d];
            const float* rowp = Ab + (size_t)r * NG;
            float uu_r = su[r];
            float bv = -1.0f; int bj = -1;
#pragma unroll
            for (int e = 0; e < 8; e++) {
                int j = (e << 6) + lane;
                if ((colFree[j >> 6] >> (j & 63)) & 1ULL) {
                    float p = expf(rowp[j] + uu_r + sv[j]);
                    if (p > bv) { bv = p; bj = j; }
                }
            }
#pragma unroll
            for (int off = 1; off < 64; off <<= 1) {
                float ov = __shfl_xor(bv, off); int oj = __shfl_xor(bj, off);
                if (ov > bv || (ov == bv && oj < bj)) { bv = ov; bj = oj; }
            }
            if (lane == 0) { rbVal[r] = bv; rbCol[r] = bj; }
        }
        __syncthreads();
    }

    permInt[b * NG + t] = sperm[t];
    permOutF[b * NG + t] = (float)sperm[t];
}

// ---------------- apply permutation: out[b][perm[r]] = in[b][r]
__global__ void scatter_coords(const float* __restrict__ src,
    const int* __restrict__ perm, float* __restrict__ dst)
{
    int tid = blockIdx.x * 256 + threadIdx.x;
    if (tid >= NB * NG) return;
    int b = tid >> 9;
    int p = perm[tid];
    size_t so = (size_t)tid * 3;
    size_t dd = ((size_t)(b << 9) + p) * 3;
    dst[dd] = src[so]; dst[dd + 1] = src[so + 1]; dst[dd + 2] = src[so + 2];
}

__global__ void scatter_feats(const float* __restrict__ src,
    const int* __restrict__ perm, float* __restrict__ dst)
{
    int tid = blockIdx.x * 256 + threadIdx.x;   // NB*NG*96 float4s
    int rc = tid / 96;
    int q = tid - rc * 96;
    int b = rc >> 9;
    int p = perm[rc];
    const float4* s4 = (const float4*)(src + (size_t)rc * NC);
    float4* d4 = (float4*)(dst + ((size_t)(b << 9) + p) * NC);
    d4[q] = s4[q];
}

extern "C" void kernel_launch(void* const* d_in, const int* in_sizes, int n_in,
                              void* d_out, int out_size, void* d_ws, size_t ws_size,
                              hipStream_t stream)
{
    const float* coords = (const float*)d_in[0];
    const float* feats  = (const float*)d_in[1];
    const float* W1 = (const float*)d_in[2];
    const float* b1 = (const float*)d_in[3];
    const float* W2 = (const float*)d_in[4];
    const float* b2 = (const float*)d_in[5];

    float* out = (float*)d_out;
    float* outCoords = out;
    float* outFeats  = out + (size_t)NB * NG * 3;
    float* outPerm   = out + (size_t)NB * NG * 3 + (size_t)NB * NG * NC;

    float* ws = (float*)d_ws;
    float* h   = ws;                                  // 16384*768
    float* A0  = h + (size_t)NB * NG * NH;            // 16384*512  (= scores/TAU)
    float* u   = A0 + (size_t)NB * NG * NG;           // 16384
    float* v   = u + NB * NG;                         // 16384
    float* pm  = v + NB * NG;                         // 32*8*512
    float* ps  = pm + NB * 8 * NG;                    // 32*8*512
    int* permInt = (int*)(ps + NB * 8 * NG);          // 16384

    const int M = NB * NG;  // 16384

    // h = relu(feats @ W1 + b1)
    gemm_bias<<<dim3((M / 64) * (NH / 64)), 256, 0, stream>>>(
        feats, W1, b1, h, M, NH, NC, 0);
    // A0 = (h @ W2 + b2) / TAU
    gemm_bias<<<dim3((M / 64) * (NG / 64)), 256, 0, stream>>>(
        h, W2, b2, A0, M, NG, NH, 1);

    hipMemsetAsync(v, 0, (size_t)NB * NG * sizeof(float), stream);

    for (int it = 0; it < 10; ++it) {
        row_lse<<<dim3(M / 4), 256, 0, stream>>>(A0, v, u);
        col_partial<<<dim3(NB * 16), 256, 0, stream>>>(A0, u, pm, ps);
        col_combine<<<dim3(M / 256), 256, 0, stream>>>(pm, ps, v);
    }

    greedy<<<dim3(NB), 512, 0, stream>>>(A0, u, v, permInt, outPerm);

    scatter_coords<<<dim3((NB * NG + 255) / 256), 256, 0, stream>>>(coords, permInt, outCoords);
    scatter_feats<<<dim3((NB * NG * 96) / 256), 256, 0, stream>>>(feats, permInt, outFeats);
}

// Round 3
// 1612.395 us; speedup vs baseline: 1.1523x; 1.1523x over previous
//
#include <hip/hip_runtime.h>
#include <math.h>

#define NB 32
#define NG 512
#define NC 384
#define NH 768

// ---------------- GEMM: C = op(A @ Bw + bias), A: MxK row-major, Bw: KxN row-major
// mode 0: relu      mode 1: divide by 0.1 (scores / TAU)
__global__ __launch_bounds__(256) void gemm_bias(
    const float* __restrict__ A, const float* __restrict__ Bw,
    const float* __restrict__ bias, float* __restrict__ Co,
    int M, int N, int K, int mode)
{
    __shared__ float sA[16][64];
    __shared__ float sB[16][64];
    int mtiles = M >> 6;
    int bm = (blockIdx.x % mtiles) << 6;
    int bn = (blockIdx.x / mtiles) << 6;
    int t = threadIdx.x;
    int tx = t & 15, ty = t >> 4;
    int la_m = t >> 2;          // 0..63
    int la_q = (t & 3) << 2;    // k offset 0,4,8,12
    int lb_k = t >> 4;          // 0..15
    int lb_n = (t & 15) << 2;   // 0..60
    const float* Aptr = A + (size_t)(bm + la_m) * K + la_q;
    const float* Bptr = Bw + (size_t)lb_k * N + bn + lb_n;
    float acc[4][4];
#pragma unroll
    for (int i = 0; i < 4; i++)
#pragma unroll
        for (int j = 0; j < 4; j++) acc[i][j] = 0.f;

    for (int k0 = 0; k0 < K; k0 += 16) {
        float4 av = *(const float4*)(Aptr + k0);
        float4 bv = *(const float4*)(Bptr + (size_t)k0 * N);
        __syncthreads();
        sA[la_q + 0][la_m] = av.x;
        sA[la_q + 1][la_m] = av.y;
        sA[la_q + 2][la_m] = av.z;
        sA[la_q + 3][la_m] = av.w;
        *(float4*)&sB[lb_k][lb_n] = bv;
        __syncthreads();
#pragma unroll
        for (int kk = 0; kk < 16; kk++) {
            float a0 = sA[kk][(ty << 2) + 0], a1 = sA[kk][(ty << 2) + 1];
            float a2 = sA[kk][(ty << 2) + 2], a3 = sA[kk][(ty << 2) + 3];
            float b0 = sB[kk][(tx << 2) + 0], b1 = sB[kk][(tx << 2) + 1];
            float b2 = sB[kk][(tx << 2) + 2], b3 = sB[kk][(tx << 2) + 3];
            acc[0][0] += a0 * b0; acc[0][1] += a0 * b1; acc[0][2] += a0 * b2; acc[0][3] += a0 * b3;
            acc[1][0] += a1 * b0; acc[1][1] += a1 * b1; acc[1][2] += a1 * b2; acc[1][3] += a1 * b3;
            acc[2][0] += a2 * b0; acc[2][1] += a2 * b1; acc[2][2] += a2 * b2; acc[2][3] += a2 * b3;
            acc[3][0] += a3 * b0; acc[3][1] += a3 * b1; acc[3][2] += a3 * b2; acc[3][3] += a3 * b3;
        }
    }
#pragma unroll
    for (int i = 0; i < 4; i++) {
        int row = bm + (ty << 2) + i;
        float vals[4];
#pragma unroll
        for (int j = 0; j < 4; j++) {
            float val = acc[i][j] + bias[bn + (tx << 2) + j];
            vals[j] = (mode == 0) ? fmaxf(val, 0.f) : val / 0.1f;
        }
        float4 o; o.x = vals[0]; o.y = vals[1]; o.z = vals[2]; o.w = vals[3];
        *(float4*)(Co + (size_t)row * N + bn + (tx << 2)) = o;
    }
}

// ---------------- Sinkhorn: u_i = -LSE_j(A0_ij + v_j)   (one wave per row)
__global__ __launch_bounds__(256) void row_lse(
    const float* __restrict__ A0, const float* __restrict__ vv,
    float* __restrict__ uu)
{
    int wid = blockIdx.x * 4 + (threadIdx.x >> 6);   // global row over NB*NG
    int lane = threadIdx.x & 63;
    int b = wid >> 9;
    const float* row = A0 + (size_t)wid * NG;
    const float* vb = vv + (b << 9);
    float x[8];
    float m = -INFINITY;
#pragma unroll
    for (int e = 0; e < 8; e++) {
        int j = (e << 6) + lane;
        x[e] = row[j] + vb[j];
        m = fmaxf(m, x[e]);
    }
#pragma unroll
    for (int off = 1; off < 64; off <<= 1) m = fmaxf(m, __shfl_xor(m, off));
    float s = 0.f;
#pragma unroll
    for (int e = 0; e < 8; e++) s += expf(x[e] - m);
#pragma unroll
    for (int off = 1; off < 64; off <<= 1) s += __shfl_xor(s, off);
    if (lane == 0) uu[wid] = -(m + logf(s));
}

// ---------------- Sinkhorn col step stage A: partial online LSE over 64-row chunks
__global__ __launch_bounds__(256) void col_partial(
    const float* __restrict__ A0, const float* __restrict__ uu,
    float* __restrict__ pm, float* __restrict__ ps)
{
    int blk = blockIdx.x;          // NB * 2 * 8 = 512 blocks
    int b = blk >> 4;
    int cc = blk & 1;
    int rc = (blk >> 1) & 7;
    int j = (cc << 8) + threadIdx.x;
    const float* base = A0 + ((size_t)(b << 9) + (rc << 6)) * NG + j;
    const float* ub = uu + (b << 9) + (rc << 6);
    float m = -INFINITY, s = 0.f;
    for (int i = 0; i < 64; i++) {
        float x = base[(size_t)i * NG] + ub[i];
        if (x > m) { s = s * expf(m - x) + 1.f; m = x; }
        else s += expf(x - m);
    }
    int o = ((b << 3) + rc) * NG + j;
    pm[o] = m; ps[o] = s;
}

// ---------------- Sinkhorn col step stage B: combine 8 partials -> v_j
__global__ __launch_bounds__(256) void col_combine(
    const float* __restrict__ pm, const float* __restrict__ ps,
    float* __restrict__ vv)
{
    int tid = blockIdx.x * 256 + threadIdx.x;  // NB*NG
    int b = tid >> 9, j = tid & 511;
    float M = -INFINITY;
#pragma unroll
    for (int rc = 0; rc < 8; rc++) M = fmaxf(M, pm[((b << 3) + rc) * NG + j]);
    float S = 0.f;
#pragma unroll
    for (int rc = 0; rc < 8; rc++) {
        int o = ((b << 3) + rc) * NG + j;
        S += ps[o] * expf(pm[o] - M);
    }
    vv[tid] = -(M + logf(S));
}

// ---------------- P = exp((A0 + u) + v), identical FP op order to round-0 greedy
__global__ __launch_bounds__(256) void compute_P(
    const float* __restrict__ A0, const float* __restrict__ uu,
    const float* __restrict__ vv, float* __restrict__ P)
{
    int tid = blockIdx.x * 256 + threadIdx.x;    // NB*NG*NG/4 threads
    int rowIdx = tid >> 7;                       // 0..16383
    int q = (tid & 127) << 2;                    // col 0..508
    int b = rowIdx >> 9;
    float ur = uu[rowIdx];
    const float* vb = vv + (b << 9);
    size_t off = ((size_t)rowIdx << 9) + q;
    float4 a = *(const float4*)(A0 + off);
    float4 o;
    o.x = expf(a.x + ur + vb[q + 0]);
    o.y = expf(a.y + ur + vb[q + 1]);
    o.z = expf(a.z + ur + vb[q + 2]);
    o.w = expf(a.w + ur + vb[q + 3]);
    *(float4*)(P + off) = o;
}

// ---------------- wave-cooperative masked row argmax (val desc, col asc)
// lane l covers cols 4l..4l+3 and 256+4l..256+4l+3. wlo/whi: free-bit words for
// this lane's low/high col group.
__device__ __forceinline__ void wave_row_argmax(
    const float* __restrict__ rowp, int l,
    unsigned long long wlo, unsigned long long whi,
    float& obv, int& obj)
{
    const float4 x0 = *(const float4*)(rowp + 4 * l);
    const float4 x1 = *(const float4*)(rowp + 256 + 4 * l);
    int sh = (l & 15) << 2;
    float bv = -1.f; int bj = 0x7FFFFFFF;
    float vv[8] = { x0.x, x0.y, x0.z, x0.w, x1.x, x1.y, x1.z, x1.w };
#pragma unroll
    for (int i = 0; i < 8; i++) {
        int j = (i < 4) ? (4 * l + i) : (256 + 4 * l + (i - 4));
        unsigned long long wmask = (i < 4) ? wlo : whi;
        bool fr = (wmask >> (sh + (i & 3))) & 1ULL;
        if (fr && vv[i] > bv) { bv = vv[i]; bj = j; }   // ascending j: lowest col on tie
    }
#pragma unroll
    for (int off = 1; off < 64; off <<= 1) {
        float ov = __shfl_xor(bv, off);
        int oj = __shfl_xor(bj, off);
        if (ov > bv || (ov == bv && oj < bj)) { bv = ov; bj = oj; }
    }
    obv = bv; obj = bj;
}

// ---------------- Greedy assignment: init with 8 waves, main loop = 1 wave,
// zero barriers. Lane l owns rows 8l..8l+7 (cached best val/col in registers).
// Exactly replicates repeated masked flat-argmax (ties: lowest r*G+c).
__global__ __launch_bounds__(512) void greedy2(
    const float* __restrict__ P, int* __restrict__ permInt,
    float* __restrict__ permOutF)
{
    int b = blockIdx.x;
    __shared__ float rbV[NG];
    __shared__ int   rbC[NG];
    int t = threadIdx.x;
    int l = t & 63;
    int w = t >> 6;
    const float* Pb = P + (size_t)b * NG * NG;

    // init: per-row unmasked argmax, 8 waves in parallel
    for (int r = w; r < NG; r += 8) {
        float bv; int bj;
        wave_row_argmax(Pb + ((size_t)r << 9), l, ~0ULL, ~0ULL, bv, bj);
        if (l == 0) { rbV[r] = bv; rbC[r] = bj; }
    }
    __syncthreads();
    if (w != 0) return;

    // wave 0 only from here on: everything in registers, no barriers
    float rv[8]; int rc[8];
#pragma unroll
    for (int k = 0; k < 8; k++) { rv[k] = rbV[8 * l + k]; rc[k] = rbC[8 * l + k]; }
    unsigned long long m[8];
#pragma unroll
    for (int k = 0; k < 8; k++) m[k] = ~0ULL;

    for (int step = 0; step < NG; ++step) {
        // local best over my 8 cached rows (val desc, flat asc)
        float bv = -1.f; int bf = 0x7FFFFFFF;
#pragma unroll
        for (int k = 0; k < 8; k++) {
            int flat = ((8 * l + k) << 9) | (rc[k] & 511);
            if (rv[k] > bv || (rv[k] == bv && flat < bf)) { bv = rv[k]; bf = flat; }
        }
        // wave argmax
#pragma unroll
        for (int off = 1; off < 64; off <<= 1) {
            float ov = __shfl_xor(bv, off);
            int of = __shfl_xor(bf, off);
            if (ov > bv || (ov == bv && of < bf)) { bv = ov; bf = of; }
        }
        int r = bf >> 9, c = bf & 511;
        if (l == 0) {
            permInt[(b << 9) + r] = c;
            permOutF[(b << 9) + r] = (float)c;
        }
        // retire row r (owner lane, static reg index)
#pragma unroll
        for (int k = 0; k < 8; k++) if (8 * l + k == r) rv[k] = -1.f;
        // take column c
        {
            int cw = c >> 6;
            unsigned long long cb = ~(1ULL << (c & 63));
#pragma unroll
            for (int k = 0; k < 8; k++) if (k == cw) m[k] &= cb;
        }
        // lazy rescan: rows whose cached argmax col was just taken
#pragma unroll
        for (int k = 0; k < 8; k++) {
            bool dirty = (rv[k] >= 0.f) && (rc[k] == c);
            unsigned long long d = __ballot(dirty);
            while (d) {
                int src = __ffsll((unsigned long long)d) - 1;
                d &= d - 1;
                int rr = src * 8 + k;
                int sel = l >> 4;
                unsigned long long wlo = sel == 0 ? m[0] : sel == 1 ? m[1] : sel == 2 ? m[2] : m[3];
                unsigned long long whi = sel == 0 ? m[4] : sel == 1 ? m[5] : sel == 2 ? m[6] : m[7];
                float nv; int nj;
                wave_row_argmax(Pb + ((size_t)rr << 9), l, wlo, whi, nv, nj);
                if (l == src) { rv[k] = nv; rc[k] = nj; }
            }
        }
    }
}

// ---------------- apply permutation: out[b][perm[r]] = in[b][r]
__global__ void scatter_coords(const float* __restrict__ src,
    const int* __restrict__ perm, float* __restrict__ dst)
{
    int tid = blockIdx.x * 256 + threadIdx.x;
    if (tid >= NB * NG) return;
    int b = tid >> 9;
    int p = perm[tid];
    size_t so = (size_t)tid * 3;
    size_t dd = ((size_t)(b << 9) + p) * 3;
    dst[dd] = src[so]; dst[dd + 1] = src[so + 1]; dst[dd + 2] = src[so + 2];
}

__global__ void scatter_feats(const float* __restrict__ src,
    const int* __restrict__ perm, float* __restrict__ dst)
{
    int tid = blockIdx.x * 256 + threadIdx.x;   // NB*NG*96 float4s
    int rc = tid / 96;
    int q = tid - rc * 96;
    int b = rc >> 9;
    int p = perm[rc];
    const float4* s4 = (const float4*)(src + (size_t)rc * NC);
    float4* d4 = (float4*)(dst + ((size_t)(b << 9) + p) * NC);
    d4[q] = s4[q];
}

extern "C" void kernel_launch(void* const* d_in, const int* in_sizes, int n_in,
                              void* d_out, int out_size, void* d_ws, size_t ws_size,
                              hipStream_t stream)
{
    const float* coords = (const float*)d_in[0];
    const float* feats  = (const float*)d_in[1];
    const float* W1 = (const float*)d_in[2];
    const float* b1 = (const float*)d_in[3];
    const float* W2 = (const float*)d_in[4];
    const float* b2 = (const float*)d_in[5];

    float* out = (float*)d_out;
    float* outCoords = out;
    float* outFeats  = out + (size_t)NB * NG * 3;
    float* outPerm   = out + (size_t)NB * NG * 3 + (size_t)NB * NG * NC;

    float* ws = (float*)d_ws;
    float* h   = ws;                                  // 16384*768 (reused as P later)
    float* A0  = h + (size_t)NB * NG * NH;            // 16384*512  (= scores/TAU)
    float* u   = A0 + (size_t)NB * NG * NG;           // 16384
    float* v   = u + NB * NG;                         // 16384
    float* pm  = v + NB * NG;                         // 32*8*512
    float* ps  = pm + NB * 8 * NG;                    // 32*8*512
    int* permInt = (int*)(ps + NB * 8 * NG);          // 16384

    const int M = NB * NG;  // 16384

    // h = relu(feats @ W1 + b1)
    gemm_bias<<<dim3((M / 64) * (NH / 64)), 256, 0, stream>>>(
        feats, W1, b1, h, M, NH, NC, 0);
    // A0 = (h @ W2 + b2) / TAU
    gemm_bias<<<dim3((M / 64) * (NG / 64)), 256, 0, stream>>>(
        h, W2, b2, A0, M, NG, NH, 1);

    hipMemsetAsync(v, 0, (size_t)NB * NG * sizeof(float), stream);

    for (int it = 0; it < 10; ++it) {
        row_lse<<<dim3(M / 4), 256, 0, stream>>>(A0, v, u);
        col_partial<<<dim3(NB * 16), 256, 0, stream>>>(A0, u, pm, ps);
        col_combine<<<dim3(M / 256), 256, 0, stream>>>(pm, ps, v);
    }

    // P = exp(A0 + u + v), reusing the h buffer (h is dead after gemm2)
    float* P = h;
    compute_P<<<dim3((M * NG / 4) / 256), 256, 0, stream>>>(A0, u, v, P);

    greedy2<<<dim3(NB), 512, 0, stream>>>(P, permInt, outPerm);

    scatter_coords<<<dim3((NB * NG + 255) / 256), 256, 0, stream>>>(coords, permInt, outCoords);
    scatter_feats<<<dim3((NB * NG * 96) / 256), 256, 0, stream>>>(feats, permInt, outFeats);
}

// Round 4
// 1382.474 us; speedup vs baseline: 1.3439x; 1.1663x over previous
//
#include <hip/hip_runtime.h>
#include <math.h>

#define NB 32
#define NG 512
#define NC 384
#define NH 768

// ---------------- GEMM: C = op(A @ Bw + bias), A: MxK row-major, Bw: KxN row-major
// mode 0: relu      mode 1: divide by 0.1 (scores / TAU)
__global__ __launch_bounds__(256) void gemm_bias(
    const float* __restrict__ A, const float* __restrict__ Bw,
    const float* __restrict__ bias, float* __restrict__ Co,
    int M, int N, int K, int mode)
{
    __shared__ float sA[16][64];
    __shared__ float sB[16][64];
    int mtiles = M >> 6;
    int bm = (blockIdx.x % mtiles) << 6;
    int bn = (blockIdx.x / mtiles) << 6;
    int t = threadIdx.x;
    int tx = t & 15, ty = t >> 4;
    int la_m = t >> 2;          // 0..63
    int la_q = (t & 3) << 2;    // k offset 0,4,8,12
    int lb_k = t >> 4;          // 0..15
    int lb_n = (t & 15) << 2;   // 0..60
    const float* Aptr = A + (size_t)(bm + la_m) * K + la_q;
    const float* Bptr = Bw + (size_t)lb_k * N + bn + lb_n;
    float acc[4][4];
#pragma unroll
    for (int i = 0; i < 4; i++)
#pragma unroll
        for (int j = 0; j < 4; j++) acc[i][j] = 0.f;

    for (int k0 = 0; k0 < K; k0 += 16) {
        float4 av = *(const float4*)(Aptr + k0);
        float4 bv = *(const float4*)(Bptr + (size_t)k0 * N);
        __syncthreads();
        sA[la_q + 0][la_m] = av.x;
        sA[la_q + 1][la_m] = av.y;
        sA[la_q + 2][la_m] = av.z;
        sA[la_q + 3][la_m] = av.w;
        *(float4*)&sB[lb_k][lb_n] = bv;
        __syncthreads();
#pragma unroll
        for (int kk = 0; kk < 16; kk++) {
            float a0 = sA[kk][(ty << 2) + 0], a1 = sA[kk][(ty << 2) + 1];
            float a2 = sA[kk][(ty << 2) + 2], a3 = sA[kk][(ty << 2) + 3];
            float b0 = sB[kk][(tx << 2) + 0], b1 = sB[kk][(tx << 2) + 1];
            float b2 = sB[kk][(tx << 2) + 2], b3 = sB[kk][(tx << 2) + 3];
            acc[0][0] += a0 * b0; acc[0][1] += a0 * b1; acc[0][2] += a0 * b2; acc[0][3] += a0 * b3;
            acc[1][0] += a1 * b0; acc[1][1] += a1 * b1; acc[1][2] += a1 * b2; acc[1][3] += a1 * b3;
            acc[2][0] += a2 * b0; acc[2][1] += a2 * b1; acc[2][2] += a2 * b2; acc[2][3] += a2 * b3;
            acc[3][0] += a3 * b0; acc[3][1] += a3 * b1; acc[3][2] += a3 * b2; acc[3][3] += a3 * b3;
        }
    }
#pragma unroll
    for (int i = 0; i < 4; i++) {
        int row = bm + (ty << 2) + i;
        float vals[4];
#pragma unroll
        for (int j = 0; j < 4; j++) {
            float val = acc[i][j] + bias[bn + (tx << 2) + j];
            vals[j] = (mode == 0) ? fmaxf(val, 0.f) : val / 0.1f;
        }
        float4 o; o.x = vals[0]; o.y = vals[1]; o.z = vals[2]; o.w = vals[3];
        *(float4*)(Co + (size_t)row * N + bn + (tx << 2)) = o;
    }
}

// ---------------- Sinkhorn: u_i = -LSE_j(A0_ij + v_j)   (one wave per row)
__global__ __launch_bounds__(256) void row_lse(
    const float* __restrict__ A0, const float* __restrict__ vv,
    float* __restrict__ uu)
{
    int wid = blockIdx.x * 4 + (threadIdx.x >> 6);   // global row over NB*NG
    int lane = threadIdx.x & 63;
    int b = wid >> 9;
    const float* row = A0 + (size_t)wid * NG;
    const float* vb = vv + (b << 9);
    float x[8];
    float m = -INFINITY;
#pragma unroll
    for (int e = 0; e < 8; e++) {
        int j = (e << 6) + lane;
        x[e] = row[j] + vb[j];
        m = fmaxf(m, x[e]);
    }
#pragma unroll
    for (int off = 1; off < 64; off <<= 1) m = fmaxf(m, __shfl_xor(m, off));
    float s = 0.f;
#pragma unroll
    for (int e = 0; e < 8; e++) s += expf(x[e] - m);
#pragma unroll
    for (int off = 1; off < 64; off <<= 1) s += __shfl_xor(s, off);
    if (lane == 0) uu[wid] = -(m + logf(s));
}

// ---------------- Sinkhorn col step stage A: partial online LSE over 64-row chunks
__global__ __launch_bounds__(256) void col_partial(
    const float* __restrict__ A0, const float* __restrict__ uu,
    float* __restrict__ pm, float* __restrict__ ps)
{
    int blk = blockIdx.x;          // NB * 2 * 8 = 512 blocks
    int b = blk >> 4;
    int cc = blk & 1;
    int rc = (blk >> 1) & 7;
    int j = (cc << 8) + threadIdx.x;
    const float* base = A0 + ((size_t)(b << 9) + (rc << 6)) * NG + j;
    const float* ub = uu + (b << 9) + (rc << 6);
    float m = -INFINITY, s = 0.f;
    for (int i = 0; i < 64; i++) {
        float x = base[(size_t)i * NG] + ub[i];
        if (x > m) { s = s * expf(m - x) + 1.f; m = x; }
        else s += expf(x - m);
    }
    int o = ((b << 3) + rc) * NG + j;
    pm[o] = m; ps[o] = s;
}

// ---------------- Sinkhorn col step stage B: combine 8 partials -> v_j
__global__ __launch_bounds__(256) void col_combine(
    const float* __restrict__ pm, const float* __restrict__ ps,
    float* __restrict__ vv)
{
    int tid = blockIdx.x * 256 + threadIdx.x;  // NB*NG
    int b = tid >> 9, j = tid & 511;
    float M = -INFINITY;
#pragma unroll
    for (int rc = 0; rc < 8; rc++) M = fmaxf(M, pm[((b << 3) + rc) * NG + j]);
    float S = 0.f;
#pragma unroll
    for (int rc = 0; rc < 8; rc++) {
        int o = ((b << 3) + rc) * NG + j;
        S += ps[o] * expf(pm[o] - M);
    }
    vv[tid] = -(M + logf(S));
}

// ======== DPP argmax reduce: (val desc, idx asc), result in lane 63 ========
// update_dpp(old=self, ...) with bound_ctrl=false: invalid/masked lanes keep
// self -> self-compare no-op; terminal lanes (15/31/47/63) only ever combine
// valid data, so lane 63 is exact. No LDS pipe, pure VALU.
#define AMAX_DPP(bv, bf, CTRL, RM)                                           \
    {                                                                        \
        int _vi = __builtin_amdgcn_update_dpp(__float_as_int(bv),            \
                      __float_as_int(bv), CTRL, RM, 0xf, false);             \
        int _fi = __builtin_amdgcn_update_dpp(bf, bf, CTRL, RM, 0xf, false); \
        float _vf = __int_as_float(_vi);                                     \
        if (_vf > bv || (_vf == bv && _fi < bf)) { bv = _vf; bf = _fi; }     \
    }

#define AMAX_REDUCE(bv, bf)       \
    AMAX_DPP(bv, bf, 0x111, 0xf)  \
    AMAX_DPP(bv, bf, 0x112, 0xf)  \
    AMAX_DPP(bv, bf, 0x114, 0xf)  \
    AMAX_DPP(bv, bf, 0x118, 0xf)  \
    AMAX_DPP(bv, bf, 0x142, 0xa)  \
    AMAX_DPP(bv, bf, 0x143, 0xc)

#define CMPSEL(vA, fA, vB, fB) \
    if (vB > vA || (vB == vA && fB < fA)) { vA = vB; fA = fB; }

// ---------------- Greedy assignment. Init (8 waves): P = exp(A0+u+v) written
// to Pb AND per-row argmax cached. Main loop (wave 0 only, zero barriers):
// register-cached per-row best, DPP wave argmax, lazy rescan from L2-hot Pb.
// Exactly replicates repeated masked flat-argmax (ties: lowest r*G+c).
__global__ __launch_bounds__(512) void greedy3(
    const float* __restrict__ A0, const float* __restrict__ uu,
    const float* __restrict__ vv, float* __restrict__ P,
    int* __restrict__ permInt, float* __restrict__ permOutF)
{
    int b = blockIdx.x;
    __shared__ float rbV[NG];
    __shared__ int   rbC[NG];
    int t = threadIdx.x;
    int l = t & 63;
    int w = t >> 6;
    const float* Ab = A0 + (size_t)b * NG * NG;
    float* Pb = P + (size_t)b * NG * NG;

    // per-lane v slice: cols 4l..4l+3 and 256+4l..256+4l+3
    float4 va = *(const float4*)(vv + (b << 9) + 4 * l);
    float4 vb = *(const float4*)(vv + (b << 9) + 256 + 4 * l);

    // ---- init: 8 waves; compute P, store it, cache per-row argmax ----
    for (int r = w; r < NG; r += 8) {
        float ur = uu[(b << 9) + r];
        size_t ro = (size_t)r << 9;
        float4 a0 = *(const float4*)(Ab + ro + 4 * l);
        float4 a1 = *(const float4*)(Ab + ro + 256 + 4 * l);
        float4 p0, p1;
        p0.x = expf(a0.x + ur + va.x);
        p0.y = expf(a0.y + ur + va.y);
        p0.z = expf(a0.z + ur + va.z);
        p0.w = expf(a0.w + ur + va.w);
        p1.x = expf(a1.x + ur + vb.x);
        p1.y = expf(a1.y + ur + vb.y);
        p1.z = expf(a1.z + ur + vb.z);
        p1.w = expf(a1.w + ur + vb.w);
        *(float4*)(Pb + ro + 4 * l) = p0;
        *(float4*)(Pb + ro + 256 + 4 * l) = p1;
        // local argmax, ascending col scan (strict > keeps lowest col on tie)
        float bv = -1.f; int bj = 0x7FFFFFFF;
        float pv[8] = { p0.x, p0.y, p0.z, p0.w, p1.x, p1.y, p1.z, p1.w };
#pragma unroll
        for (int i = 0; i < 8; i++) {
            int j = (i < 4) ? (4 * l + i) : (256 + 4 * l + (i - 4));
            if (pv[i] > bv) { bv = pv[i]; bj = j; }
        }
        AMAX_REDUCE(bv, bj)
        if (l == 63) { rbV[r] = bv; rbC[r] = bj; }
    }
    __syncthreads();
    if (w != 0) return;

    // ---- wave 0 only: all state in registers, no barriers ----
    float rv[8]; int rc[8];
#pragma unroll
    for (int k = 0; k < 8; k++) { rv[k] = rbV[8 * l + k]; rc[k] = rbC[8 * l + k]; }
    unsigned long long m[8];
#pragma unroll
    for (int k = 0; k < 8; k++) m[k] = ~0ULL;

    for (int step = 0; step < NG; ++step) {
        // local best over my 8 cached rows: depth-3 tree (val desc, flat asc)
        float av[8]; int af[8];
#pragma unroll
        for (int k = 0; k < 8; k++) {
            av[k] = rv[k];
            af[k] = ((8 * l + k) << 9) | (rc[k] & 511);
        }
        CMPSEL(av[0], af[0], av[1], af[1])
        CMPSEL(av[2], af[2], av[3], af[3])
        CMPSEL(av[4], af[4], av[5], af[5])
        CMPSEL(av[6], af[6], av[7], af[7])
        CMPSEL(av[0], af[0], av[2], af[2])
        CMPSEL(av[4], af[4], av[6], af[6])
        CMPSEL(av[0], af[0], av[4], af[4])
        float bv = av[0]; int bf = af[0];
        AMAX_REDUCE(bv, bf)
        int bestf = __builtin_amdgcn_readlane(bf, 63);
        int r = bestf >> 9, c = bestf & 511;
        if (l == 0) {
            permInt[(b << 9) + r] = c;
            permOutF[(b << 9) + r] = (float)c;
        }
        // retire row r (owner lane, static reg index)
#pragma unroll
        for (int k = 0; k < 8; k++) if (8 * l + k == r) rv[k] = -1.f;
        // take column c
        {
            int cw = c >> 6;
            unsigned long long cb = ~(1ULL << (c & 63));
#pragma unroll
            for (int k = 0; k < 8; k++) if (k == cw) m[k] &= cb;
        }
        // lazy rescan: rows whose cached argmax col was just taken
#pragma unroll
        for (int k = 0; k < 8; k++) {
            bool dirty = (rv[k] >= 0.f) && (rc[k] == c);
            unsigned long long d = __ballot(dirty);
            while (d) {
                int src = __ffsll((unsigned long long)d) - 1;
                d &= d - 1;
                int rr = src * 8 + k;
                const float* rowp = Pb + ((size_t)rr << 9);
                float4 x0 = *(const float4*)(rowp + 4 * l);
                float4 x1 = *(const float4*)(rowp + 256 + 4 * l);
                int sel = l >> 4;
                unsigned long long wlo = sel == 0 ? m[0] : sel == 1 ? m[1] : sel == 2 ? m[2] : m[3];
                unsigned long long whi = sel == 0 ? m[4] : sel == 1 ? m[5] : sel == 2 ? m[6] : m[7];
                int sh = (l & 15) << 2;
                float bv2 = -1.f; int bj2 = 0x7FFFFFFF;
                float pv[8] = { x0.x, x0.y, x0.z, x0.w, x1.x, x1.y, x1.z, x1.w };
#pragma unroll
                for (int i = 0; i < 8; i++) {
                    int j = (i < 4) ? (4 * l + i) : (256 + 4 * l + (i - 4));
                    unsigned long long wm = (i < 4) ? wlo : whi;
                    bool fr = (wm >> (sh + (i & 3))) & 1ULL;
                    if (fr && pv[i] > bv2) { bv2 = pv[i]; bj2 = j; }
                }
                AMAX_REDUCE(bv2, bj2)
                int nvi = __builtin_amdgcn_readlane(__float_as_int(bv2), 63);
                int nj  = __builtin_amdgcn_readlane(bj2, 63);
                if (l == src) { rv[k] = __int_as_float(nvi); rc[k] = nj; }
            }
        }
    }
}

// ---------------- apply permutation: out[b][perm[r]] = in[b][r]
__global__ void scatter_coords(const float* __restrict__ src,
    const int* __restrict__ perm, float* __restrict__ dst)
{
    int tid = blockIdx.x * 256 + threadIdx.x;
    if (tid >= NB * NG) return;
    int b = tid >> 9;
    int p = perm[tid];
    size_t so = (size_t)tid * 3;
    size_t dd = ((size_t)(b << 9) + p) * 3;
    dst[dd] = src[so]; dst[dd + 1] = src[so + 1]; dst[dd + 2] = src[so + 2];
}

__global__ void scatter_feats(const float* __restrict__ src,
    const int* __restrict__ perm, float* __restrict__ dst)
{
    int tid = blockIdx.x * 256 + threadIdx.x;   // NB*NG*96 float4s
    int rc = tid / 96;
    int q = tid - rc * 96;
    int b = rc >> 9;
    int p = perm[rc];
    const float4* s4 = (const float4*)(src + (size_t)rc * NC);
    float4* d4 = (float4*)(dst + ((size_t)(b << 9) + p) * NC);
    d4[q] = s4[q];
}

extern "C" void kernel_launch(void* const* d_in, const int* in_sizes, int n_in,
                              void* d_out, int out_size, void* d_ws, size_t ws_size,
                              hipStream_t stream)
{
    const float* coords = (const float*)d_in[0];
    const float* feats  = (const float*)d_in[1];
    const float* W1 = (const float*)d_in[2];
    const float* b1 = (const float*)d_in[3];
    const float* W2 = (const float*)d_in[4];
    const float* b2 = (const float*)d_in[5];

    float* out = (float*)d_out;
    float* outCoords = out;
    float* outFeats  = out + (size_t)NB * NG * 3;
    float* outPerm   = out + (size_t)NB * NG * 3 + (size_t)NB * NG * NC;

    float* ws = (float*)d_ws;
    float* h   = ws;                                  // 16384*768 (reused as P later)
    float* A0  = h + (size_t)NB * NG * NH;            // 16384*512  (= scores/TAU)
    float* u   = A0 + (size_t)NB * NG * NG;           // 16384
    float* v   = u + NB * NG;                         // 16384
    float* pm  = v + NB * NG;                         // 32*8*512
    float* ps  = pm + NB * 8 * NG;                    // 32*8*512
    int* permInt = (int*)(ps + NB * 8 * NG);          // 16384

    const int M = NB * NG;  // 16384

    // h = relu(feats @ W1 + b1)
    gemm_bias<<<dim3((M / 64) * (NH / 64)), 256, 0, stream>>>(
        feats, W1, b1, h, M, NH, NC, 0);
    // A0 = (h @ W2 + b2) / TAU
    gemm_bias<<<dim3((M / 64) * (NG / 64)), 256, 0, stream>>>(
        h, W2, b2, A0, M, NG, NH, 1);

    hipMemsetAsync(v, 0, (size_t)NB * NG * sizeof(float), stream);

    for (int it = 0; it < 10; ++it) {
        row_lse<<<dim3(M / 4), 256, 0, stream>>>(A0, v, u);
        col_partial<<<dim3(NB * 16), 256, 0, stream>>>(A0, u, pm, ps);
        col_combine<<<dim3(M / 256), 256, 0, stream>>>(pm, ps, v);
    }

    // P = exp(A0 + u + v) is computed inside greedy3's init pass (fused),
    // reusing the h buffer (dead after gemm2).
    float* P = h;
    greedy3<<<dim3(NB), 512, 0, stream>>>(A0, u, v, P, permInt, outPerm);

    scatter_coords<<<dim3((NB * NG + 255) / 256), 256, 0, stream>>>(coords, permInt, outCoords);
    scatter_feats<<<dim3((NB * NG * 96) / 256), 256, 0, stream>>>(feats, permInt, outFeats);
}

// Round 5
// 1125.766 us; speedup vs baseline: 1.6503x; 1.2280x over previous
//
#include <hip/hip_runtime.h>
#include <math.h>

#define NB 32
#define NG 512
#define NC 384
#define NH 768

// ---------------- GEMM: C = op(A @ Bw + bias), A: MxK row-major, Bw: KxN row-major
// mode 0: relu      mode 1: divide by 0.1 (scores / TAU)
__global__ __launch_bounds__(256) void gemm_bias(
    const float* __restrict__ A, const float* __restrict__ Bw,
    const float* __restrict__ bias, float* __restrict__ Co,
    int M, int N, int K, int mode)
{
    __shared__ float sA[16][64];
    __shared__ float sB[16][64];
    int mtiles = M >> 6;
    int bm = (blockIdx.x % mtiles) << 6;
    int bn = (blockIdx.x / mtiles) << 6;
    int t = threadIdx.x;
    int tx = t & 15, ty = t >> 4;
    int la_m = t >> 2;          // 0..63
    int la_q = (t & 3) << 2;    // k offset 0,4,8,12
    int lb_k = t >> 4;          // 0..15
    int lb_n = (t & 15) << 2;   // 0..60
    const float* Aptr = A + (size_t)(bm + la_m) * K + la_q;
    const float* Bptr = Bw + (size_t)lb_k * N + bn + lb_n;
    float acc[4][4];
#pragma unroll
    for (int i = 0; i < 4; i++)
#pragma unroll
        for (int j = 0; j < 4; j++) acc[i][j] = 0.f;

    for (int k0 = 0; k0 < K; k0 += 16) {
        float4 av = *(const float4*)(Aptr + k0);
        float4 bv = *(const float4*)(Bptr + (size_t)k0 * N);
        __syncthreads();
        sA[la_q + 0][la_m] = av.x;
        sA[la_q + 1][la_m] = av.y;
        sA[la_q + 2][la_m] = av.z;
        sA[la_q + 3][la_m] = av.w;
        *(float4*)&sB[lb_k][lb_n] = bv;
        __syncthreads();
#pragma unroll
        for (int kk = 0; kk < 16; kk++) {
            float a0 = sA[kk][(ty << 2) + 0], a1 = sA[kk][(ty << 2) + 1];
            float a2 = sA[kk][(ty << 2) + 2], a3 = sA[kk][(ty << 2) + 3];
            float b0 = sB[kk][(tx << 2) + 0], b1 = sB[kk][(tx << 2) + 1];
            float b2 = sB[kk][(tx << 2) + 2], b3 = sB[kk][(tx << 2) + 3];
            acc[0][0] += a0 * b0; acc[0][1] += a0 * b1; acc[0][2] += a0 * b2; acc[0][3] += a0 * b3;
            acc[1][0] += a1 * b0; acc[1][1] += a1 * b1; acc[1][2] += a1 * b2; acc[1][3] += a1 * b3;
            acc[2][0] += a2 * b0; acc[2][1] += a2 * b1; acc[2][2] += a2 * b2; acc[2][3] += a2 * b3;
            acc[3][0] += a3 * b0; acc[3][1] += a3 * b1; acc[3][2] += a3 * b2; acc[3][3] += a3 * b3;
        }
    }
#pragma unroll
    for (int i = 0; i < 4; i++) {
        int row = bm + (ty << 2) + i;
        float vals[4];
#pragma unroll
        for (int j = 0; j < 4; j++) {
            float val = acc[i][j] + bias[bn + (tx << 2) + j];
            vals[j] = (mode == 0) ? fmaxf(val, 0.f) : val / 0.1f;
        }
        float4 o; o.x = vals[0]; o.y = vals[1]; o.z = vals[2]; o.w = vals[3];
        *(float4*)(Co + (size_t)row * N + bn + (tx << 2)) = o;
    }
}

// ---------------- Sinkhorn: u_i = -LSE_j(A0_ij + v_j)   (one wave per row)
__global__ __launch_bounds__(256) void row_lse(
    const float* __restrict__ A0, const float* __restrict__ vv,
    float* __restrict__ uu)
{
    int wid = blockIdx.x * 4 + (threadIdx.x >> 6);   // global row over NB*NG
    int lane = threadIdx.x & 63;
    int b = wid >> 9;
    const float* row = A0 + (size_t)wid * NG;
    const float* vb = vv + (b << 9);
    float x[8];
    float m = -INFINITY;
#pragma unroll
    for (int e = 0; e < 8; e++) {
        int j = (e << 6) + lane;
        x[e] = row[j] + vb[j];
        m = fmaxf(m, x[e]);
    }
#pragma unroll
    for (int off = 1; off < 64; off <<= 1) m = fmaxf(m, __shfl_xor(m, off));
    float s = 0.f;
#pragma unroll
    for (int e = 0; e < 8; e++) s += expf(x[e] - m);
#pragma unroll
    for (int off = 1; off < 64; off <<= 1) s += __shfl_xor(s, off);
    if (lane == 0) uu[wid] = -(m + logf(s));
}

// ---------------- Sinkhorn col step stage A: partial online LSE over 64-row chunks
__global__ __launch_bounds__(256) void col_partial(
    const float* __restrict__ A0, const float* __restrict__ uu,
    float* __restrict__ pm, float* __restrict__ ps)
{
    int blk = blockIdx.x;          // NB * 2 * 8 = 512 blocks
    int b = blk >> 4;
    int cc = blk & 1;
    int rc = (blk >> 1) & 7;
    int j = (cc << 8) + threadIdx.x;
    const float* base = A0 + ((size_t)(b << 9) + (rc << 6)) * NG + j;
    const float* ub = uu + (b << 9) + (rc << 6);
    float m = -INFINITY, s = 0.f;
    for (int i = 0; i < 64; i++) {
        float x = base[(size_t)i * NG] + ub[i];
        if (x > m) { s = s * expf(m - x) + 1.f; m = x; }
        else s += expf(x - m);
    }
    int o = ((b << 3) + rc) * NG + j;
    pm[o] = m; ps[o] = s;
}

// ---------------- Sinkhorn col step stage B: combine 8 partials -> v_j
__global__ __launch_bounds__(256) void col_combine(
    const float* __restrict__ pm, const float* __restrict__ ps,
    float* __restrict__ vv)
{
    int tid = blockIdx.x * 256 + threadIdx.x;  // NB*NG
    int b = tid >> 9, j = tid & 511;
    float M = -INFINITY;
#pragma unroll
    for (int rc = 0; rc < 8; rc++) M = fmaxf(M, pm[((b << 3) + rc) * NG + j]);
    float S = 0.f;
#pragma unroll
    for (int rc = 0; rc < 8; rc++) {
        int o = ((b << 3) + rc) * NG + j;
        S += ps[o] * expf(pm[o] - M);
    }
    vv[tid] = -(M + logf(S));
}

// ======== two-phase DPP reduce networks (to lane 63) ========
#define DPP6_MAXF(x)                                                              \
    { int _t;                                                                     \
      _t = __builtin_amdgcn_update_dpp(__float_as_int(x), __float_as_int(x),      \
               0x111, 0xf, 0xf, false); x = fmaxf(x, __int_as_float(_t));         \
      _t = __builtin_amdgcn_update_dpp(__float_as_int(x), __float_as_int(x),      \
               0x112, 0xf, 0xf, false); x = fmaxf(x, __int_as_float(_t));         \
      _t = __builtin_amdgcn_update_dpp(__float_as_int(x), __float_as_int(x),      \
               0x114, 0xf, 0xf, false); x = fmaxf(x, __int_as_float(_t));         \
      _t = __builtin_amdgcn_update_dpp(__float_as_int(x), __float_as_int(x),      \
               0x118, 0xf, 0xf, false); x = fmaxf(x, __int_as_float(_t));         \
      _t = __builtin_amdgcn_update_dpp(__float_as_int(x), __float_as_int(x),      \
               0x142, 0xa, 0xf, false); x = fmaxf(x, __int_as_float(_t));         \
      _t = __builtin_amdgcn_update_dpp(__float_as_int(x), __float_as_int(x),      \
               0x143, 0xc, 0xf, false); x = fmaxf(x, __int_as_float(_t)); }

#define DPP6_MINI(x)                                                              \
    { int _t;                                                                     \
      _t = __builtin_amdgcn_update_dpp(x, x, 0x111, 0xf, 0xf, false);             \
      x = (x < _t) ? x : _t;                                                      \
      _t = __builtin_amdgcn_update_dpp(x, x, 0x112, 0xf, 0xf, false);             \
      x = (x < _t) ? x : _t;                                                      \
      _t = __builtin_amdgcn_update_dpp(x, x, 0x114, 0xf, 0xf, false);             \
      x = (x < _t) ? x : _t;                                                      \
      _t = __builtin_amdgcn_update_dpp(x, x, 0x118, 0xf, 0xf, false);             \
      x = (x < _t) ? x : _t;                                                      \
      _t = __builtin_amdgcn_update_dpp(x, x, 0x142, 0xa, 0xf, false);             \
      x = (x < _t) ? x : _t;                                                      \
      _t = __builtin_amdgcn_update_dpp(x, x, 0x143, 0xc, 0xf, false);             \
      x = (x < _t) ? x : _t; }

// ---------------- P = exp((A0+u)+v) + per-row argmax (val desc, col asc).
// One wave per row; grid-wide (all CUs). Memory-bound.
__global__ __launch_bounds__(256) void p_rowmax(
    const float* __restrict__ A0, const float* __restrict__ uu,
    const float* __restrict__ vv, float* __restrict__ P,
    float* __restrict__ rbV, int* __restrict__ rbC)
{
    int wrow = blockIdx.x * 4 + (threadIdx.x >> 6);  // 0..16383
    int l = threadIdx.x & 63;
    int b = wrow >> 9;
    float ur = uu[wrow];
    const float* vb = vv + (b << 9);
    size_t ro = (size_t)wrow << 9;
    float4 a0 = *(const float4*)(A0 + ro + 4 * l);
    float4 a1 = *(const float4*)(A0 + ro + 256 + 4 * l);
    float4 v0 = *(const float4*)(vb + 4 * l);
    float4 v1 = *(const float4*)(vb + 256 + 4 * l);
    float p0 = expf(a0.x + ur + v0.x);
    float p1 = expf(a0.y + ur + v0.y);
    float p2 = expf(a0.z + ur + v0.z);
    float p3 = expf(a0.w + ur + v0.w);
    float p4 = expf(a1.x + ur + v1.x);
    float p5 = expf(a1.y + ur + v1.y);
    float p6 = expf(a1.z + ur + v1.z);
    float p7 = expf(a1.w + ur + v1.w);
    float4 o0; o0.x = p0; o0.y = p1; o0.z = p2; o0.w = p3;
    float4 o1; o1.x = p4; o1.y = p5; o1.z = p6; o1.w = p7;
    *(float4*)(P + ro + 4 * l) = o0;
    *(float4*)(P + ro + 256 + 4 * l) = o1;
    // local max + lowest-col select (descending chain keeps lowest col on tie)
    float mv = fmaxf(fmaxf(fmaxf(p0, p1), fmaxf(p2, p3)),
                     fmaxf(fmaxf(p4, p5), fmaxf(p6, p7)));
    int cb = 4 * l;
    int f = 0x7FFFFFFF;
    f = (p7 == mv) ? 256 + cb + 3 : f;
    f = (p6 == mv) ? 256 + cb + 2 : f;
    f = (p5 == mv) ? 256 + cb + 1 : f;
    f = (p4 == mv) ? 256 + cb + 0 : f;
    f = (p3 == mv) ? cb + 3 : f;
    f = (p2 == mv) ? cb + 2 : f;
    f = (p1 == mv) ? cb + 1 : f;
    f = (p0 == mv) ? cb + 0 : f;
    float g = mv;
    DPP6_MAXF(g)
    int gi = __builtin_amdgcn_readlane(__float_as_int(g), 63);
    float gm = __int_as_float(gi);
    int fs = (mv == gm) ? f : 0x7FFFFFFF;
    DPP6_MINI(fs)
    if (l == 63) { rbV[wrow] = gm; rbC[wrow] = fs; }
}

// ---------------- Greedy assignment: 1 wave per batch, no barriers, no LDS.
// Lane l owns rows 8l..8l+7 (rv=val, rf=(row<<9)|col, bit30=dead) and cols
// 4l..4l+3, 256+4l..+3 (free8 bits 0-3 / 4-7). Exactly replicates repeated
// masked flat-argmax (ties: lowest r*G+c).
__global__ __launch_bounds__(64) void greedy4(
    const float* __restrict__ P, const float* __restrict__ rbV,
    const int* __restrict__ rbC, int* __restrict__ permInt)
{
    int b = blockIdx.x;
    int l = threadIdx.x;
    const float* Pb = P + (size_t)b * NG * NG;

    float rv[8]; int rf[8];
    {
        const float* rvp = rbV + (b << 9) + 8 * l;
        const int* rcp = rbC + (b << 9) + 8 * l;
        float4 va = *(const float4*)(rvp);
        float4 vb = *(const float4*)(rvp + 4);
        int4 ca = *(const int4*)(rcp);
        int4 cb = *(const int4*)(rcp + 4);
        int base = (8 * l) << 9;
        rv[0] = va.x; rf[0] = (base + (0 << 9)) | ca.x;
        rv[1] = va.y; rf[1] = (base + (1 << 9)) | ca.y;
        rv[2] = va.z; rf[2] = (base + (2 << 9)) | ca.z;
        rv[3] = va.w; rf[3] = (base + (3 << 9)) | ca.w;
        rv[4] = vb.x; rf[4] = (base + (4 << 9)) | cb.x;
        rv[5] = vb.y; rf[5] = (base + (5 << 9)) | cb.y;
        rv[6] = vb.z; rf[6] = (base + (6 << 9)) | cb.z;
        rv[7] = vb.w; rf[7] = (base + (7 << 9)) | cb.w;
    }
    unsigned int free8 = 0xFF;

    for (int step = 0; step < NG; ++step) {
        // local best over my 8 rows (max val; lowest row on tie via desc chain)
        float mv = fmaxf(fmaxf(fmaxf(rv[0], rv[1]), fmaxf(rv[2], rv[3])),
                         fmaxf(fmaxf(rv[4], rv[5]), fmaxf(rv[6], rv[7])));
        int f = 0x7FFFFFFF;
        f = (rv[7] == mv) ? rf[7] : f;
        f = (rv[6] == mv) ? rf[6] : f;
        f = (rv[5] == mv) ? rf[5] : f;
        f = (rv[4] == mv) ? rf[4] : f;
        f = (rv[3] == mv) ? rf[3] : f;
        f = (rv[2] == mv) ? rf[2] : f;
        f = (rv[1] == mv) ? rf[1] : f;
        f = (rv[0] == mv) ? rf[0] : f;
        // wave reduce: max val, then min flat among tied lanes
        float g = mv;
        DPP6_MAXF(g)
        int gi = __builtin_amdgcn_readlane(__float_as_int(g), 63);
        float gm = __int_as_float(gi);
        int fs = (mv == gm) ? f : 0x7FFFFFFF;
        DPP6_MINI(fs)
        int bestf = __builtin_amdgcn_readlane(fs, 63);
        int r = bestf >> 9, c = bestf & 511;
        if (l == 0) permInt[(b << 9) + r] = c;
        // take column c (per-lane free mask)
        int owner = (c & 255) >> 2;
        int bit = (c & 3) | ((c & 256) >> 6);
        if (l == owner) free8 &= ~(1u << bit);
        int deadf = bestf | (1 << 30);
        // dirty detect: alive rows (bit30 clear) whose cached col == c.
        // Includes the just-taken row (retired inside the loop below).
        int dm = 0;
#pragma unroll
        for (int k = 0; k < 8; k++)
            dm |= ((((rf[k] ^ c) & 0x400001FF) == 0) ? 1 : 0) << k;
        unsigned long long dd = __ballot(dm != 0);
        while (dd) {
            int src = __ffsll(dd) - 1; dd &= dd - 1;
            int dmk = __builtin_amdgcn_readlane(dm, src);
            while (dmk) {
                int kk = __ffs(dmk) - 1; dmk &= dmk - 1;
                int rr = (src << 3) + kk;
                float nv; int nf;
                if (rr == r) {
                    nv = -1.0f; nf = deadf;   // retire the taken row
                } else {
                    // rescan row rr over free cols
                    const float* rowp = Pb + ((size_t)rr << 9);
                    float4 x0 = *(const float4*)(rowp + 4 * l);
                    float4 x1 = *(const float4*)(rowp + 256 + 4 * l);
                    float q0 = (free8 & 1u)   ? x0.x : -1.0f;
                    float q1 = (free8 & 2u)   ? x0.y : -1.0f;
                    float q2 = (free8 & 4u)   ? x0.z : -1.0f;
                    float q3 = (free8 & 8u)   ? x0.w : -1.0f;
                    float q4 = (free8 & 16u)  ? x1.x : -1.0f;
                    float q5 = (free8 & 32u)  ? x1.y : -1.0f;
                    float q6 = (free8 & 64u)  ? x1.z : -1.0f;
                    float q7 = (free8 & 128u) ? x1.w : -1.0f;
                    float lm = fmaxf(fmaxf(fmaxf(q0, q1), fmaxf(q2, q3)),
                                     fmaxf(fmaxf(q4, q5), fmaxf(q6, q7)));
                    int sb = rr << 9;
                    int cb = 4 * l;
                    int lf = 0x7FFFFFFF;
                    lf = (q7 == lm) ? sb + 256 + cb + 3 : lf;
                    lf = (q6 == lm) ? sb + 256 + cb + 2 : lf;
                    lf = (q5 == lm) ? sb + 256 + cb + 1 : lf;
                    lf = (q4 == lm) ? sb + 256 + cb + 0 : lf;
                    lf = (q3 == lm) ? sb + cb + 3 : lf;
                    lf = (q2 == lm) ? sb + cb + 2 : lf;
                    lf = (q1 == lm) ? sb + cb + 1 : lf;
                    lf = (q0 == lm) ? sb + cb + 0 : lf;
                    float gg = lm;
                    DPP6_MAXF(gg)
                    int ggi = __builtin_amdgcn_readlane(__float_as_int(gg), 63);
                    float ggm = __int_as_float(ggi);
                    int lfs = (lm == ggm) ? lf : 0x7FFFFFFF;
                    DPP6_MINI(lfs)
                    nf = __builtin_amdgcn_readlane(lfs, 63);
                    nv = ggm;
                }
                if (l == src) {
                    switch (kk) {
                        case 0: rv[0] = nv; rf[0] = nf; break;
                        case 1: rv[1] = nv; rf[1] = nf; break;
                        case 2: rv[2] = nv; rf[2] = nf; break;
                        case 3: rv[3] = nv; rf[3] = nf; break;
                        case 4: rv[4] = nv; rf[4] = nf; break;
                        case 5: rv[5] = nv; rf[5] = nf; break;
                        case 6: rv[6] = nv; rf[6] = nf; break;
                        case 7: rv[7] = nv; rf[7] = nf; break;
                    }
                }
            }
        }
    }
}

// ---------------- apply permutation: out[b][perm[r]] = in[b][r]
__global__ void scatter_coords(const float* __restrict__ src,
    const int* __restrict__ perm, float* __restrict__ dst,
    float* __restrict__ permF)
{
    int tid = blockIdx.x * 256 + threadIdx.x;
    if (tid >= NB * NG) return;
    int b = tid >> 9;
    int p = perm[tid];
    permF[tid] = (float)p;
    size_t so = (size_t)tid * 3;
    size_t dd = ((size_t)(b << 9) + p) * 3;
    dst[dd] = src[so]; dst[dd + 1] = src[so + 1]; dst[dd + 2] = src[so + 2];
}

__global__ void scatter_feats(const float* __restrict__ src,
    const int* __restrict__ perm, float* __restrict__ dst)
{
    int tid = blockIdx.x * 256 + threadIdx.x;   // NB*NG*96 float4s
    int rc = tid / 96;
    int q = tid - rc * 96;
    int b = rc >> 9;
    int p = perm[rc];
    const float4* s4 = (const float4*)(src + (size_t)rc * NC);
    float4* d4 = (float4*)(dst + ((size_t)(b << 9) + p) * NC);
    d4[q] = s4[q];
}

extern "C" void kernel_launch(void* const* d_in, const int* in_sizes, int n_in,
                              void* d_out, int out_size, void* d_ws, size_t ws_size,
                              hipStream_t stream)
{
    const float* coords = (const float*)d_in[0];
    const float* feats  = (const float*)d_in[1];
    const float* W1 = (const float*)d_in[2];
    const float* b1 = (const float*)d_in[3];
    const float* W2 = (const float*)d_in[4];
    const float* b2 = (const float*)d_in[5];

    float* out = (float*)d_out;
    float* outCoords = out;
    float* outFeats  = out + (size_t)NB * NG * 3;
    float* outPerm   = out + (size_t)NB * NG * 3 + (size_t)NB * NG * NC;

    float* ws = (float*)d_ws;
    float* h   = ws;                                  // 16384*768 (reused as P later)
    float* A0  = h + (size_t)NB * NG * NH;            // 16384*512  (= scores/TAU)
    float* u   = A0 + (size_t)NB * NG * NG;           // 16384
    float* v   = u + NB * NG;                         // 16384
    float* pm  = v + NB * NG;                         // 32*8*512
    float* ps  = pm + NB * 8 * NG;                    // 32*8*512
    float* rbV = ps + NB * 8 * NG;                    // 16384
    int* rbC   = (int*)(rbV + NB * NG);               // 16384
    int* permInt = (int*)(rbC + NB * NG);             // 16384

    const int M = NB * NG;  // 16384

    // h = relu(feats @ W1 + b1)
    gemm_bias<<<dim3((M / 64) * (NH / 64)), 256, 0, stream>>>(
        feats, W1, b1, h, M, NH, NC, 0);
    // A0 = (h @ W2 + b2) / TAU
    gemm_bias<<<dim3((M / 64) * (NG / 64)), 256, 0, stream>>>(
        h, W2, b2, A0, M, NG, NH, 1);

    hipMemsetAsync(v, 0, (size_t)NB * NG * sizeof(float), stream);

    for (int it = 0; it < 10; ++it) {
        row_lse<<<dim3(M / 4), 256, 0, stream>>>(A0, v, u);
        col_partial<<<dim3(NB * 16), 256, 0, stream>>>(A0, u, pm, ps);
        col_combine<<<dim3(M / 256), 256, 0, stream>>>(pm, ps, v);
    }

    // P = exp(A0+u+v) + per-row argmax (grid-wide, memory-bound)
    float* P = h;
    p_rowmax<<<dim3(M / 4), 256, 0, stream>>>(A0, u, v, P, rbV, rbC);

    greedy4<<<dim3(NB), 64, 0, stream>>>(P, rbV, rbC, permInt);

    scatter_coords<<<dim3((NB * NG + 255) / 256), 256, 0, stream>>>(coords, permInt, outCoords, outPerm);
    scatter_feats<<<dim3((NB * NG * 96) / 256), 256, 0, stream>>>(feats, permInt, outFeats);
}